// Round 2
// baseline (876.610 us; speedup 1.0000x reference)
//
#include <hip/hip_runtime.h>
#include <hip/hip_bf16.h>

using f16 = _Float16;
typedef __attribute__((ext_vector_type(8))) f16 half8;
typedef __attribute__((ext_vector_type(4))) float floatx4;

#define LN_EPS 1e-5f

// ---------------------------------------------------------------------------
// async global->LDS, 16B per lane. LDS dest is wave-uniform base + lane*16.
// ---------------------------------------------------------------------------
__device__ __forceinline__ void gload_lds16(const f16* g, f16* l) {
  __builtin_amdgcn_global_load_lds(
      (const __attribute__((address_space(1))) void*)g,
      (__attribute__((address_space(3))) void*)l, 16, 0, 0);
}

// ---------------------------------------------------------------------------
// fp32 -> fp16 elementwise convert (n divisible by 1024)
// ---------------------------------------------------------------------------
__global__ void convert_f32_f16(const float* __restrict__ in,
                                f16* __restrict__ out, int n) {
  const int i = (blockIdx.x * 256 + threadIdx.x) * 4;
  const float4 f = *(const float4*)(in + i);
  out[i + 0] = (f16)f.x;
  out[i + 1] = (f16)f.y;
  out[i + 2] = (f16)f.z;
  out[i + 3] = (f16)f.w;
}

// ---------------------------------------------------------------------------
// fp32 [R,C] -> fp16 [C,R] tiled transpose+convert. block (32,8), grid (C/32,R/32)
// ---------------------------------------------------------------------------
__global__ void transpose_f32_f16(const float* __restrict__ in,
                                  f16* __restrict__ out, int R, int C) {
  __shared__ float tile[32][33];
  const int c0 = blockIdx.x * 32, r0 = blockIdx.y * 32;
  const int tx = threadIdx.x, ty = threadIdx.y;
#pragma unroll
  for (int i = 0; i < 32; i += 8)
    tile[ty + i][tx] = in[(size_t)(r0 + ty + i) * C + (c0 + tx)];
  __syncthreads();
#pragma unroll
  for (int i = 0; i < 32; i += 8)
    out[(size_t)(c0 + ty + i) * R + (r0 + tx)] = (f16)tile[tx][ty + i];
}

// ---------------------------------------------------------------------------
// NT GEMM: C[M,N] = A[M,K] * B[N,K]^T, fp16 inputs, fp32 accumulate.
// 128x128 tile, BK=32, 256 threads (4 waves), each wave 64x64 via 4x4 MFMA.
// EPI: 0 = fp32 store, 1 = fp16 store, 2 = bias+relu -> fp16 store.
// M,N divisible by 128; K divisible by 32.
// ---------------------------------------------------------------------------
template <int EPI>
__global__ void gemm_nt(const f16* __restrict__ A, const f16* __restrict__ B,
                        float* __restrict__ Cf, f16* __restrict__ Ch,
                        const float* __restrict__ bias, int M, int N, int K) {
  __shared__ f16 As[128 * 32];
  __shared__ f16 Bs[128 * 32];
  const int t = threadIdx.x;
  const int wave = t >> 6, lane = t & 63;
  const int wm = (wave >> 1) << 6;   // wave row offset (0/64)
  const int wn = (wave & 1) << 6;    // wave col offset (0/64)
  const int bm = blockIdx.y << 7, bn = blockIdx.x << 7;
  const int lrow = lane & 15;        // fragment m/n within 16
  const int lkc = lane >> 4;         // k-chunk 0..3

  floatx4 acc[4][4] = {};

  // staging: thread t loads 8 f16 (16B); 4 threads per 32-elem row
  const int sr = t >> 2;             // row 0..63 (first half)
  const int sc = (t & 3) << 3;       // k-offset 0/8/16/24
  const f16* Ag = A + (size_t)(bm + sr) * K + sc;
  const f16* Bg = B + (size_t)(bn + sr) * K + sc;
  f16* AsW = As + t * 8;             // == wave base + lane*16B
  f16* BsW = Bs + t * 8;

  const f16* ApL = As + (wm + lrow) * 32 + lkc * 8;
  const f16* BpL = Bs + (wn + lrow) * 32 + lkc * 8;

  for (int k0 = 0; k0 < K; k0 += 32) {
    gload_lds16(Ag, AsW);
    gload_lds16(Ag + (size_t)64 * K, AsW + 2048);
    gload_lds16(Bg, BsW);
    gload_lds16(Bg + (size_t)64 * K, BsW + 2048);
    Ag += 32;
    Bg += 32;
    __syncthreads();
    half8 af[4], bfr[4];
#pragma unroll
    for (int i = 0; i < 4; ++i) af[i] = *(const half8*)(ApL + i * (16 * 32));
#pragma unroll
    for (int j = 0; j < 4; ++j) bfr[j] = *(const half8*)(BpL + j * (16 * 32));
#pragma unroll
    for (int i = 0; i < 4; ++i)
#pragma unroll
      for (int j = 0; j < 4; ++j)
        acc[i][j] = __builtin_amdgcn_mfma_f32_16x16x32_f16(af[i], bfr[j],
                                                           acc[i][j], 0, 0, 0);
    __syncthreads();
  }

  // C/D layout: col = lane&15, row = (lane>>4)*4 + reg  [m89/m91 verified]
  const int crow0 = bm + wm + lkc * 4;
  const int ccol0 = bn + wn + lrow;
#pragma unroll
  for (int i = 0; i < 4; ++i) {
#pragma unroll
    for (int r = 0; r < 4; ++r) {
      const size_t row = (size_t)(crow0 + i * 16 + r);
#pragma unroll
      for (int j = 0; j < 4; ++j) {
        const int col = ccol0 + j * 16;
        float v = acc[i][j][r];
        if (EPI == 2) v = fmaxf(v + bias[col], 0.0f);
        if (EPI == 0)
          Cf[row * N + col] = v;
        else
          Ch[row * N + col] = (f16)v;
      }
    }
  }
}

// ---------------------------------------------------------------------------
// row softmax: fp32 S[row,:N] -> fp16 P. One 256-thread block per row, N=4096.
// ---------------------------------------------------------------------------
__global__ void softmax_rows(const float* __restrict__ S, f16* __restrict__ P,
                             int N) {
  const int row = blockIdx.x;
  const int t = threadIdx.x;
  const int lane = t & 63, wave = t >> 6;
  const float* s = S + (size_t)row * N;
  float v[16];
  float mx = -1e30f;
#pragma unroll
  for (int i = 0; i < 4; ++i) {
    const float4 f = *(const float4*)(s + i * 1024 + t * 4);
    v[i * 4 + 0] = f.x; v[i * 4 + 1] = f.y;
    v[i * 4 + 2] = f.z; v[i * 4 + 3] = f.w;
    mx = fmaxf(mx, fmaxf(fmaxf(f.x, f.y), fmaxf(f.z, f.w)));
  }
#pragma unroll
  for (int off = 32; off > 0; off >>= 1) mx = fmaxf(mx, __shfl_xor(mx, off));
  __shared__ float red[8];
  if (lane == 0) red[wave] = mx;
  __syncthreads();
  mx = fmaxf(fmaxf(red[0], red[1]), fmaxf(red[2], red[3]));
  float sum = 0.0f;
#pragma unroll
  for (int i = 0; i < 16; ++i) {
    v[i] = __expf(v[i] - mx);
    sum += v[i];
  }
#pragma unroll
  for (int off = 32; off > 0; off >>= 1) sum += __shfl_xor(sum, off);
  if (lane == 0) red[4 + wave] = sum;
  __syncthreads();
  const float inv = 1.0f / (red[4] + red[5] + red[6] + red[7]);
  f16* p = P + (size_t)row * N;
#pragma unroll
  for (int i = 0; i < 4; ++i)
#pragma unroll
    for (int jj = 0; jj < 4; ++jj)
      p[i * 1024 + t * 4 + jj] = (f16)(v[i * 4 + jj] * inv);
}

// ---------------------------------------------------------------------------
// fused residual + (optional bias) + LayerNorm. One block per row, D=1024.
// outf (fp32) and/or outh (fp16) may be null.
// ---------------------------------------------------------------------------
__global__ void add_ln(const float* __restrict__ a, const float* __restrict__ b,
                       const float* __restrict__ bias, const float* __restrict__ g,
                       const float* __restrict__ be, float* __restrict__ outf,
                       f16* __restrict__ outh, int D) {
  const int row = blockIdx.x;
  const int t = threadIdx.x;
  const int lane = t & 63, wave = t >> 6;
  const float4 av = *(const float4*)(a + (size_t)row * D + t * 4);
  const float4 bv = *(const float4*)(b + (size_t)row * D + t * 4);
  float s[4] = {av.x + bv.x, av.y + bv.y, av.z + bv.z, av.w + bv.w};
  if (bias != nullptr) {
    const float4 bb = *(const float4*)(bias + t * 4);
    s[0] += bb.x; s[1] += bb.y; s[2] += bb.z; s[3] += bb.w;
  }
  float sum = s[0] + s[1] + s[2] + s[3];
  float sq = s[0] * s[0] + s[1] * s[1] + s[2] * s[2] + s[3] * s[3];
#pragma unroll
  for (int off = 32; off > 0; off >>= 1) {
    sum += __shfl_xor(sum, off);
    sq += __shfl_xor(sq, off);
  }
  __shared__ float red[8];
  if (lane == 0) {
    red[wave] = sum;
    red[4 + wave] = sq;
  }
  __syncthreads();
  sum = red[0] + red[1] + red[2] + red[3];
  sq = red[4] + red[5] + red[6] + red[7];
  const float mu = sum / (float)D;
  const float rv = rsqrtf(sq / (float)D - mu * mu + LN_EPS);
  const float4 gv = *(const float4*)(g + t * 4);
  const float4 bev = *(const float4*)(be + t * 4);
  float y0 = (s[0] - mu) * rv * gv.x + bev.x;
  float y1 = (s[1] - mu) * rv * gv.y + bev.y;
  float y2 = (s[2] - mu) * rv * gv.z + bev.z;
  float y3 = (s[3] - mu) * rv * gv.w + bev.w;
  if (outf != nullptr) {
    float4 o = {y0, y1, y2, y3};
    *(float4*)(outf + (size_t)row * D + t * 4) = o;
  }
  if (outh != nullptr) {
    f16* ob = outh + (size_t)row * D + t * 4;
    ob[0] = (f16)y0;
    ob[1] = (f16)y1;
    ob[2] = (f16)y2;
    ob[3] = (f16)y3;
  }
}

// ---------------------------------------------------------------------------
// launch
// ---------------------------------------------------------------------------
extern "C" void kernel_launch(void* const* d_in, const int* in_sizes, int n_in,
                              void* d_out, int out_size, void* d_ws,
                              size_t ws_size, hipStream_t stream) {
  constexpr int N = 4096, D = 1024, H = 4096;
  const float* x = (const float*)d_in[0];
  const float* Wq = (const float*)d_in[1];
  const float* Wk = (const float*)d_in[2];
  const float* Wv = (const float*)d_in[3];
  const float* Wo = (const float*)d_in[4];
  const float* W1 = (const float*)d_in[5];
  const float* b1 = (const float*)d_in[6];
  const float* W2 = (const float*)d_in[7];
  const float* b2 = (const float*)d_in[8];
  const float* g1 = (const float*)d_in[9];
  const float* be1 = (const float*)d_in[10];
  const float* g2 = (const float*)d_in[11];
  const float* be2 = (const float*)d_in[12];
  float* out = (float*)d_out;

  const size_t MB = 1024ull * 1024ull;
  char* w = (char*)d_ws;
  // workspace layout (256 MB total, with hazard-checked reuse)
  f16* xb  = (f16*)(w + 0 * MB);    // 8 MB  [N,D]
  f16* WqT = (f16*)(w + 8 * MB);    // 8 MB  [H,D]
  f16* WkT = (f16*)(w + 16 * MB);   // 8 MB  [H,D]
  f16* WvT = (f16*)(w + 24 * MB);   // 8 MB  [H,D]
  f16* WoT = (f16*)(w + 32 * MB);   // 8 MB  [D,H]
  f16* W1T = (f16*)(w + 40 * MB);   // 8 MB  [H,D]
  f16* W2T = (f16*)(w + 48 * MB);   // 8 MB  [D,H]
  f16* q   = (f16*)(w + 56 * MB);   // 32 MB [N,H]; reused as AH after S
  f16* kk  = (f16*)(w + 88 * MB);   // 32 MB [N,H]; reused as F1 after S
  f16* vT  = (f16*)(w + 120 * MB);  // 32 MB [H,N]
  float* S  = (float*)(w + 152 * MB); // 64 MB [N,N]; reused below after softmax
  f16* Pb  = (f16*)(w + 216 * MB);  // 32 MB [N,N]
  f16* hb  = (f16*)(w + 248 * MB);  // 8 MB  [N,D]
  float* attn = (float*)(w + 152 * MB); // 16 MB [N,D] (in S region)
  float* hf   = (float*)(w + 168 * MB); // 16 MB [N,D] (in S region)
  float* F2   = (float*)(w + 184 * MB); // 16 MB [N,D] (in S region)
  f16* AH = q;   // [N,H]
  f16* F1 = kk;  // [N,H]

  const dim3 tb32(32, 8);

  // ---- precision casts / weight transposes ----
  convert_f32_f16<<<(N * D) / 1024, 256, 0, stream>>>(x, xb, N * D);
  transpose_f32_f16<<<dim3(H / 32, D / 32), tb32, 0, stream>>>(Wq, WqT, D, H);
  transpose_f32_f16<<<dim3(H / 32, D / 32), tb32, 0, stream>>>(Wk, WkT, D, H);
  transpose_f32_f16<<<dim3(H / 32, D / 32), tb32, 0, stream>>>(Wv, WvT, D, H);
  transpose_f32_f16<<<dim3(D / 32, H / 32), tb32, 0, stream>>>(Wo, WoT, H, D);
  transpose_f32_f16<<<dim3(H / 32, D / 32), tb32, 0, stream>>>(W1, W1T, D, H);
  transpose_f32_f16<<<dim3(D / 32, H / 32), tb32, 0, stream>>>(W2, W2T, H, D);

  // ---- attention ----
  // q = xb @ WqT^T  [N,H]
  gemm_nt<1><<<dim3(H / 128, N / 128), 256, 0, stream>>>(xb, WqT, nullptr, q,
                                                         nullptr, N, H, D);
  // k = xb @ WkT^T  [N,H]
  gemm_nt<1><<<dim3(H / 128, N / 128), 256, 0, stream>>>(xb, WkT, nullptr, kk,
                                                         nullptr, N, H, D);
  // vT = WvT @ xb^T [H,N]
  gemm_nt<1><<<dim3(N / 128, H / 128), 256, 0, stream>>>(WvT, xb, nullptr, vT,
                                                         nullptr, H, N, D);
  // S = q @ k^T  [N,N] fp32
  gemm_nt<0><<<dim3(N / 128, N / 128), 256, 0, stream>>>(q, kk, S, nullptr,
                                                         nullptr, N, N, H);
  softmax_rows<<<N, 256, 0, stream>>>(S, Pb, N);
  // AH = P @ v = Pb @ vT^T  [N,H]
  gemm_nt<1><<<dim3(H / 128, N / 128), 256, 0, stream>>>(Pb, vT, nullptr, AH,
                                                         nullptr, N, H, N);
  // attn = AH @ Wo = AH @ WoT^T  [N,D] fp32
  gemm_nt<0><<<dim3(D / 128, N / 128), 256, 0, stream>>>(AH, WoT, attn, nullptr,
                                                         nullptr, N, D, H);
  // h = LN(x + attn)
  add_ln<<<N, 256, 0, stream>>>(x, attn, nullptr, g1, be1, hf, hb, D);

  // ---- feed-forward ----
  // F1 = relu(h @ W1 + b1) = relu(hb @ W1T^T + b1)  [N,H] fp16
  gemm_nt<2><<<dim3(H / 128, N / 128), 256, 0, stream>>>(hb, W1T, nullptr, F1,
                                                         b1, N, H, D);
  // F2 = F1 @ W2 = F1 @ W2T^T  [N,D] fp32
  gemm_nt<0><<<dim3(D / 128, N / 128), 256, 0, stream>>>(F1, W2T, F2, nullptr,
                                                         nullptr, N, D, H);
  // out = LN(h + F2 + b2)
  add_ln<<<N, 256, 0, stream>>>(hf, F2, b2, g2, be2, out, nullptr, D);
}

// Round 3
// 807.389 us; speedup vs baseline: 1.0857x; 1.0857x over previous
//
#include <hip/hip_runtime.h>
#include <hip/hip_bf16.h>

using f16 = _Float16;
typedef __attribute__((ext_vector_type(8))) f16 half8;
typedef __attribute__((ext_vector_type(4))) float floatx4;

#define LN_EPS 1e-5f

// ---------------------------------------------------------------------------
// async global->LDS, 16B per lane. LDS dest is wave-uniform base + lane*16.
// ---------------------------------------------------------------------------
__device__ __forceinline__ void gload_lds16(const f16* g, f16* l) {
  __builtin_amdgcn_global_load_lds(
      (const __attribute__((address_space(1))) void*)g,
      (__attribute__((address_space(3))) void*)l, 16, 0, 0);
}

// ---------------------------------------------------------------------------
// fp32 -> fp16 elementwise convert (n divisible by 1024)
// ---------------------------------------------------------------------------
__global__ void convert_f32_f16(const float* __restrict__ in,
                                f16* __restrict__ out, int n) {
  const int i = (blockIdx.x * 256 + threadIdx.x) * 4;
  const float4 f = *(const float4*)(in + i);
  out[i + 0] = (f16)f.x;
  out[i + 1] = (f16)f.y;
  out[i + 2] = (f16)f.z;
  out[i + 3] = (f16)f.w;
}

// ---------------------------------------------------------------------------
// batched fp32 [R,C] -> fp16 [C,R] transpose+convert. block (32,8),
// grid (C/32, R/32, nmat); per-z src/dst selected from args.
// ---------------------------------------------------------------------------
__global__ void transpose_f32_f16_x4(const float* s0, const float* s1,
                                     const float* s2, const float* s3,
                                     f16* d0, f16* d1, f16* d2, f16* d3,
                                     int R, int C) {
  __shared__ float tile[32][33];
  const int z = blockIdx.z;
  const float* in = (z == 0) ? s0 : (z == 1) ? s1 : (z == 2) ? s2 : s3;
  f16* out = (z == 0) ? d0 : (z == 1) ? d1 : (z == 2) ? d2 : d3;
  const int c0 = blockIdx.x * 32, r0 = blockIdx.y * 32;
  const int tx = threadIdx.x, ty = threadIdx.y;
#pragma unroll
  for (int i = 0; i < 32; i += 8)
    tile[ty + i][tx] = in[(size_t)(r0 + ty + i) * C + (c0 + tx)];
  __syncthreads();
#pragma unroll
  for (int i = 0; i < 32; i += 8)
    out[(size_t)(c0 + ty + i) * R + (r0 + tx)] = (f16)tile[tx][ty + i];
}

// ---------------------------------------------------------------------------
// NT GEMM: C[M,Nc] = A[M,K] * B[Nc,K]^T, fp16 in, fp32 accum, strided (lda/
// ldb/ldc in elements). Split-K via gridDim.z: chunk z covers K/gridDim.z,
// fp32 partials stacked at Cf + z*M*ldc (EPI 0 only).
// 128x128 tile, BK=32, 256 threads (4 waves), wave 64x64 via 4x4 MFMA.
// EPI: 0 = fp32 store, 1 = fp16 store, 2 = bias+relu -> fp16 store.
// ---------------------------------------------------------------------------
template <int EPI>
__global__ void gemm_nt(const f16* __restrict__ A, const f16* __restrict__ B,
                        float* __restrict__ Cf, f16* __restrict__ Ch,
                        const float* __restrict__ bias, int M, int Nc, int K,
                        int lda, int ldb, int ldc) {
  __shared__ f16 As[128 * 32];
  __shared__ f16 Bs[128 * 32];
  const int t = threadIdx.x;
  const int wave = t >> 6, lane = t & 63;
  const int wm = (wave >> 1) << 6;   // wave row offset (0/64)
  const int wn = (wave & 1) << 6;    // wave col offset (0/64)
  const int bm = blockIdx.y << 7, bn = blockIdx.x << 7;
  const int lrow = lane & 15;        // fragment m/n within 16
  const int lkc = lane >> 4;         // k-chunk 0..3

  const int kper = K / gridDim.z;    // K-span of this z-chunk
  const int kbeg = blockIdx.z * kper;

  floatx4 acc[4][4] = {};

  // staging: thread t loads 8 f16 (16B); 4 threads per 32-elem k-row
  const int sr = t >> 2;             // row 0..63 (first half)
  const int sc = (t & 3) << 3;       // k-offset 0/8/16/24
  const f16* Ag = A + (size_t)(bm + sr) * lda + kbeg + sc;
  const f16* Bg = B + (size_t)(bn + sr) * ldb + kbeg + sc;
  f16* AsW = As + t * 8;             // == wave base + lane*16B
  f16* BsW = Bs + t * 8;

  const f16* ApL = As + (wm + lrow) * 32 + lkc * 8;
  const f16* BpL = Bs + (wn + lrow) * 32 + lkc * 8;

  for (int kit = 0; kit < kper; kit += 32) {
    gload_lds16(Ag, AsW);
    gload_lds16(Ag + (size_t)64 * lda, AsW + 2048);
    gload_lds16(Bg, BsW);
    gload_lds16(Bg + (size_t)64 * ldb, BsW + 2048);
    Ag += 32;
    Bg += 32;
    __syncthreads();
    half8 af[4], bfr[4];
#pragma unroll
    for (int i = 0; i < 4; ++i) af[i] = *(const half8*)(ApL + i * (16 * 32));
#pragma unroll
    for (int j = 0; j < 4; ++j) bfr[j] = *(const half8*)(BpL + j * (16 * 32));
#pragma unroll
    for (int i = 0; i < 4; ++i)
#pragma unroll
      for (int j = 0; j < 4; ++j)
        acc[i][j] = __builtin_amdgcn_mfma_f32_16x16x32_f16(af[i], bfr[j],
                                                           acc[i][j], 0, 0, 0);
    __syncthreads();
  }

  float* Cfz = Cf + (size_t)blockIdx.z * M * ldc;  // split-K partial slab
  // C/D layout: col = lane&15, row = (lane>>4)*4 + reg  [m89/m91 verified]
  const int crow0 = bm + wm + lkc * 4;
  const int ccol0 = bn + wn + lrow;
#pragma unroll
  for (int i = 0; i < 4; ++i) {
#pragma unroll
    for (int r = 0; r < 4; ++r) {
      const size_t row = (size_t)(crow0 + i * 16 + r);
#pragma unroll
      for (int j = 0; j < 4; ++j) {
        const int col = ccol0 + j * 16;
        float v = acc[i][j][r];
        if (EPI == 2) v = fmaxf(v + bias[col], 0.0f);
        if (EPI == 0)
          Cfz[row * ldc + col] = v;
        else
          Ch[row * (size_t)ldc + col] = (f16)v;
      }
    }
  }
}

// ---------------------------------------------------------------------------
// row softmax: fp32 S[row,:N] -> fp16 P. One 256-thread block per row, N=4096.
// ---------------------------------------------------------------------------
__global__ void softmax_rows(const float* __restrict__ S, f16* __restrict__ P,
                             int N) {
  const int row = blockIdx.x;
  const int t = threadIdx.x;
  const int lane = t & 63, wave = t >> 6;
  const float* s = S + (size_t)row * N;
  float v[16];
  float mx = -1e30f;
#pragma unroll
  for (int i = 0; i < 4; ++i) {
    const float4 f = *(const float4*)(s + i * 1024 + t * 4);
    v[i * 4 + 0] = f.x; v[i * 4 + 1] = f.y;
    v[i * 4 + 2] = f.z; v[i * 4 + 3] = f.w;
    mx = fmaxf(mx, fmaxf(fmaxf(f.x, f.y), fmaxf(f.z, f.w)));
  }
#pragma unroll
  for (int off = 32; off > 0; off >>= 1) mx = fmaxf(mx, __shfl_xor(mx, off));
  __shared__ float red[8];
  if (lane == 0) red[wave] = mx;
  __syncthreads();
  mx = fmaxf(fmaxf(red[0], red[1]), fmaxf(red[2], red[3]));
  float sum = 0.0f;
#pragma unroll
  for (int i = 0; i < 16; ++i) {
    v[i] = __expf(v[i] - mx);
    sum += v[i];
  }
#pragma unroll
  for (int off = 32; off > 0; off >>= 1) sum += __shfl_xor(sum, off);
  if (lane == 0) red[4 + wave] = sum;
  __syncthreads();
  const float inv = 1.0f / (red[4] + red[5] + red[6] + red[7]);
  f16* p = P + (size_t)row * N;
#pragma unroll
  for (int i = 0; i < 4; ++i)
#pragma unroll
    for (int jj = 0; jj < 4; ++jj)
      p[i * 1024 + t * 4 + jj] = (f16)(v[i * 4 + jj] * inv);
}

// ---------------------------------------------------------------------------
// fused residual + split-K partial reduce + (optional bias) + LayerNorm.
// One block per row, D=1024. b = base of nchunks fp32 slabs, stride cs elems.
// outf (fp32) and/or outh (fp16) may be null.
// ---------------------------------------------------------------------------
__global__ void add_ln(const float* __restrict__ a, const float* __restrict__ b,
                       int nchunks, size_t cs, const float* __restrict__ bias,
                       const float* __restrict__ g, const float* __restrict__ be,
                       float* __restrict__ outf, f16* __restrict__ outh, int D) {
  const int row = blockIdx.x;
  const int t = threadIdx.x;
  const int lane = t & 63, wave = t >> 6;
  const float4 av = *(const float4*)(a + (size_t)row * D + t * 4);
  float s[4] = {av.x, av.y, av.z, av.w};
  for (int c = 0; c < nchunks; ++c) {
    const float4 bv = *(const float4*)(b + c * cs + (size_t)row * D + t * 4);
    s[0] += bv.x; s[1] += bv.y; s[2] += bv.z; s[3] += bv.w;
  }
  if (bias != nullptr) {
    const float4 bb = *(const float4*)(bias + t * 4);
    s[0] += bb.x; s[1] += bb.y; s[2] += bb.z; s[3] += bb.w;
  }
  float sum = s[0] + s[1] + s[2] + s[3];
  float sq = s[0] * s[0] + s[1] * s[1] + s[2] * s[2] + s[3] * s[3];
#pragma unroll
  for (int off = 32; off > 0; off >>= 1) {
    sum += __shfl_xor(sum, off);
    sq += __shfl_xor(sq, off);
  }
  __shared__ float red[8];
  if (lane == 0) {
    red[wave] = sum;
    red[4 + wave] = sq;
  }
  __syncthreads();
  sum = red[0] + red[1] + red[2] + red[3];
  sq = red[4] + red[5] + red[6] + red[7];
  const float mu = sum / (float)D;
  const float rv = rsqrtf(sq / (float)D - mu * mu + LN_EPS);
  const float4 gv = *(const float4*)(g + t * 4);
  const float4 bev = *(const float4*)(be + t * 4);
  float y0 = (s[0] - mu) * rv * gv.x + bev.x;
  float y1 = (s[1] - mu) * rv * gv.y + bev.y;
  float y2 = (s[2] - mu) * rv * gv.z + bev.z;
  float y3 = (s[3] - mu) * rv * gv.w + bev.w;
  if (outf != nullptr) {
    float4 o = {y0, y1, y2, y3};
    *(float4*)(outf + (size_t)row * D + t * 4) = o;
  }
  if (outh != nullptr) {
    f16* ob = outh + (size_t)row * D + t * 4;
    ob[0] = (f16)y0;
    ob[1] = (f16)y1;
    ob[2] = (f16)y2;
    ob[3] = (f16)y3;
  }
}

// ---------------------------------------------------------------------------
// launch
// ---------------------------------------------------------------------------
extern "C" void kernel_launch(void* const* d_in, const int* in_sizes, int n_in,
                              void* d_out, int out_size, void* d_ws,
                              size_t ws_size, hipStream_t stream) {
  constexpr int N = 4096, D = 1024, H = 4096;
  const float* x = (const float*)d_in[0];
  const float* Wq = (const float*)d_in[1];
  const float* Wk = (const float*)d_in[2];
  const float* Wv = (const float*)d_in[3];
  const float* Wo = (const float*)d_in[4];
  const float* W1 = (const float*)d_in[5];
  const float* b1 = (const float*)d_in[6];
  const float* W2 = (const float*)d_in[7];
  const float* b2 = (const float*)d_in[8];
  const float* g1 = (const float*)d_in[9];
  const float* be1 = (const float*)d_in[10];
  const float* g2 = (const float*)d_in[11];
  const float* be2 = (const float*)d_in[12];
  float* out = (float*)d_out;

  const size_t MB = 1024ull * 1024ull;
  char* w = (char*)d_ws;
  // workspace layout (256 MB, hazard-checked reuse; offsets in MB):
  f16* xb   = (f16*)(w + 0 * MB);     // 8   [N,D]
  f16* WqT  = (f16*)(w + 8 * MB);     // 8   [H,D]  -- WqT/WkT contiguous [2H,D]
  f16* WkT  = (f16*)(w + 16 * MB);    // 8   [H,D]
  f16* WvT  = (f16*)(w + 24 * MB);    // 8   [H,D]
  f16* WoT  = (f16*)(w + 32 * MB);    // 8   [D,H]
  f16* W1T  = (f16*)(w + 40 * MB);    // 8   [H,D]
  f16* W2T  = (f16*)(w + 48 * MB);    // 8   [D,H]
  f16* qk   = (f16*)(w + 56 * MB);    // 64  [N,2H] (q | k); dead after S
  f16* AH   = (f16*)(w + 56 * MB);    // 32  [N,H]  (PV out, over dead qk)
  f16* F1   = (f16*)(w + 88 * MB);    // 32  [N,H]  (over dead k half)
  f16* vT   = (f16*)(w + 120 * MB);   // 32  [H,N]
  float* S  = (float*)(w + 152 * MB); // 64  [N,N]; then attn/F2 split-K slabs
  float* par= (float*)(w + 152 * MB); // 4 x [N,D] fp32 partial slabs
  f16* Pb   = (f16*)(w + 216 * MB);   // 32  [N,N]; dead after PV
  float* hf = (float*)(w + 216 * MB); // 16  [N,D]  (over dead Pb)
  f16* hb   = (f16*)(w + 248 * MB);   // 8   [N,D]

  const dim3 tb32(32, 8);

  // ---- casts / weight transposes (3 launches) ----
  convert_f32_f16<<<(N * D) / 1024, 256, 0, stream>>>(x, xb, N * D);
  transpose_f32_f16_x4<<<dim3(H / 32, D / 32, 4), tb32, 0, stream>>>(
      Wq, Wk, Wv, W1, WqT, WkT, WvT, W1T, D, H);
  transpose_f32_f16_x4<<<dim3(D / 32, H / 32, 2), tb32, 0, stream>>>(
      Wo, W2, nullptr, nullptr, WoT, W2T, nullptr, nullptr, H, D);

  // ---- attention ----
  // [q|k] = xb @ [WqT;WkT]^T  [N,2H], ldc=2H
  gemm_nt<1><<<dim3(2 * H / 128, N / 128, 1), 256, 0, stream>>>(
      xb, WqT, nullptr, qk, nullptr, N, 2 * H, D, D, D, 2 * H);
  // vT = WvT @ xb^T  [H,N]
  gemm_nt<1><<<dim3(N / 128, H / 128, 1), 256, 0, stream>>>(
      WvT, xb, nullptr, vT, nullptr, H, N, D, D, D, N);
  // S = q @ k^T  [N,N] fp32 (q,k strided in qk, ld=2H)
  gemm_nt<0><<<dim3(N / 128, N / 128, 1), 256, 0, stream>>>(
      qk, qk + H, S, nullptr, nullptr, N, N, H, 2 * H, 2 * H, N);
  softmax_rows<<<N, 256, 0, stream>>>(S, Pb, N);
  // AH = P @ vT^T  [N,H] (overwrites dead qk)
  gemm_nt<1><<<dim3(H / 128, N / 128, 1), 256, 0, stream>>>(
      Pb, vT, nullptr, AH, nullptr, N, H, N, N, N, H);
  // attn partials = AH @ WoT^T  [N,D] fp32, split-K=4 (grid.z)
  gemm_nt<0><<<dim3(D / 128, N / 128, 4), 256, 0, stream>>>(
      AH, WoT, par, nullptr, nullptr, N, D, H, H, H, D);
  // h = LN(x + sum(attn partials))
  add_ln<<<N, 256, 0, stream>>>(x, par, 4, (size_t)N * D, nullptr, g1, be1,
                                hf, hb, D);

  // ---- feed-forward ----
  // F1 = relu(hb @ W1T^T + b1)  [N,H] fp16
  gemm_nt<2><<<dim3(H / 128, N / 128, 1), 256, 0, stream>>>(
      hb, W1T, nullptr, F1, b1, N, H, D, D, D, H);
  // F2 partials = F1 @ W2T^T  [N,D] fp32, split-K=4
  gemm_nt<0><<<dim3(D / 128, N / 128, 4), 256, 0, stream>>>(
      F1, W2T, par, nullptr, nullptr, N, D, H, H, H, D);
  // out = LN(hf + sum(F2 partials) + b2)
  add_ln<<<N, 256, 0, stream>>>(hf, par, 4, (size_t)N * D, b2, g2, be2,
                                out, nullptr, D);
}